// Round 1
// baseline (786.020 us; speedup 1.0000x reference)
//
#include <hip/hip_runtime.h>

// SetEncoderPointNet — two-kernel split-precision bf16 MFMA version.
//
// Shapes: x (8,256,256,64) f32; w1 (256,64); b1 (256); w2 (256,320); out (8,256,256,256).
// Restructure: out = x @ w2[:, :64]^T + v,  v[bn] = (max_m(x@w1^T) + b1) @ w2[:, 64:]^T.
//
// Previous fused one-block-per-bn kernel was latency-bound (~295 us vs ~105 us roofline):
// 2 waves/SIMD occupancy + a long serial chain (phase1 -> reduce -> LDS restage -> GEMV
// -> phase2) kept both MFMA and HBM pipes under ~30% utilization. Split into:
//   pointnet_v   : phase-1 + max + GEMV -> v (2 MB). No LDS weight staging (w1 planes
//                  read from L2), 9 KB LDS, 4 waves/SIMD.
//   pointnet_out : pure streaming GEMM out = x@w2x^T + v. Weights staged in LDS once,
//                  one barrier, then a free-running dt loop; stores spread across the
//                  whole kernel. 74.8 KB LDS -> 2 blocks/CU x 8 waves = 4 waves/SIMD.
// Cost: x is read twice (+128 MiB, partly L3-absorbed) — buys removal of all
// mid-kernel serialization.

#define CIN  64
#define KPAD 72            // padded k-stride in LDS (16B-aligned rows, breaks pow2 banks)
#define PLANE 18432        // 256 * 72 shorts per LDS plane

typedef __attribute__((ext_vector_type(8))) short short8;
typedef __attribute__((ext_vector_type(4))) float float4v;

__device__ __forceinline__ short f2bf(float f) {
    union { float f; unsigned u; } c; c.f = f;
    unsigned u = c.u;
    unsigned r = (u + 0x7FFFu + ((u >> 16) & 1u)) >> 16;  // round-to-nearest-even
    return (short)r;
}
__device__ __forceinline__ float bf2f(short s) {
    union { unsigned u; float f; } c;
    c.u = ((unsigned)(unsigned short)s) << 16;
    return c.f;
}

// ---- prep: split weights to bf16 hi/lo planes, transpose w2z ----
// ws layout (bytes): [0: w1 hi 32K | 32K: w1 lo 32K | 64K: w2x hi 32K | 96K: w2x lo 32K |
//                     128K: w2zt fp32 256x256 = 256K | 384K: v 2048x256 fp32 = 2 MB]
__global__ void prep_weights(const float* __restrict__ w1,
                             const float* __restrict__ w2,
                             short* __restrict__ wsS) {
    int i = blockIdx.x * 256 + threadIdx.x;
    if (i < 16384) {                       // w1 [d][k] row-major, used as-is
        float f = w1[i];
        short h = f2bf(f);
        wsS[i] = h;
        wsS[16384 + i] = f2bf(f - bf2f(h));
    } else if (i < 32768) {                // w2x: first 64 cols of w2 rows
        int q = i - 16384;
        int j = q >> 6, k = q & 63;
        float f = w2[j * 320 + k];
        short h = f2bf(f);
        wsS[32768 + q] = h;
        wsS[49152 + q] = f2bf(f - bf2f(h));
    } else if (i < 98304) {                // w2zt[d][j] = w2[j][64+d], fp32
        int q = i - 32768;
        int d = q >> 8, j = q & 255;
        ((float*)(wsS + 65536))[q] = w2[j * 320 + 64 + d];
    }
}

// ================= kernel V: v[bn][j] = (max_m(x@w1^T)+b1) . w2zt[:,j] =================
// grid 2048 (one bn per block), 512 threads = 8 waves, 32 m-rows per wave.
// B-frags (w1 hi/lo) read directly from global (128 KB region, L2-resident, reused 2048x).
// LDS: red 8 KB + zv 1 KB -> occupancy VGPR-limited at 4 waves/SIMD.
__global__ __launch_bounds__(512, 4)
void pointnet_v(const float* __restrict__ x,
                const float* __restrict__ b1,
                const short* __restrict__ w1p,   // hi @0, lo @+16384 shorts
                const float* __restrict__ w2zt,
                float* __restrict__ vout) {
    __shared__ float red[2048];
    __shared__ float zv[256];
    const int tid = threadIdx.x;
    const int bn  = blockIdx.x;
    const int w   = tid >> 6;           // wave id 0..7 -> m rows [32w, 32w+32)
    const int l   = tid & 63;
    const int dl  = l & 15;             // MFMA col lane
    const int q   = l >> 4;             // MFMA quad
    const int mw  = w * 32;
    const float* __restrict__ xg = x + (size_t)bn * (256 * CIN);

    // ---- A-frags: rows mw+t*16+dl, k = s*32+q*8 .. +7, split to bf16 hi/lo ----
    short8 ahi[2][2], alo[2][2];
#pragma unroll
    for (int t = 0; t < 2; ++t)
#pragma unroll
        for (int s = 0; s < 2; ++s) {
            const float* p = xg + (mw + t * 16 + dl) * CIN + s * 32 + q * 8;
            float4 x0 = *(const float4*)p;
            float4 x1 = *(const float4*)(p + 4);
            float e[8];
            e[0] = x0.x; e[1] = x0.y; e[2] = x0.z; e[3] = x0.w;
            e[4] = x1.x; e[5] = x1.y; e[6] = x1.z; e[7] = x1.w;
#pragma unroll
            for (int j = 0; j < 8; ++j) {
                short h = f2bf(e[j]);
                ahi[t][s][j] = h;
                alo[t][s][j] = f2bf(e[j] - bf2f(h));
            }
        }

    // ---- phase 1: z = x@w1^T (3-pass split), max over the wave's 32 rows ----
#pragma unroll 2
    for (int dt = 0; dt < 16; ++dt) {
        const short* bp = w1p + (dt * 16 + dl) * CIN + q * 8;
        short8 bh0 = *(const short8*)bp;
        short8 bh1 = *(const short8*)(bp + 32);
        short8 bl0 = *(const short8*)(bp + 16384);
        short8 bl1 = *(const short8*)(bp + 16384 + 32);
        float mx = -3.0e38f;
#pragma unroll
        for (int t = 0; t < 2; ++t) {
            float4v a = {0.f, 0.f, 0.f, 0.f};
            a = __builtin_amdgcn_mfma_f32_16x16x32_bf16(ahi[t][0], bh0, a, 0, 0, 0);
            a = __builtin_amdgcn_mfma_f32_16x16x32_bf16(ahi[t][0], bl0, a, 0, 0, 0);
            a = __builtin_amdgcn_mfma_f32_16x16x32_bf16(alo[t][0], bh0, a, 0, 0, 0);
            a = __builtin_amdgcn_mfma_f32_16x16x32_bf16(ahi[t][1], bh1, a, 0, 0, 0);
            a = __builtin_amdgcn_mfma_f32_16x16x32_bf16(ahi[t][1], bl1, a, 0, 0, 0);
            a = __builtin_amdgcn_mfma_f32_16x16x32_bf16(alo[t][1], bh1, a, 0, 0, 0);
            mx = fmaxf(mx, fmaxf(fmaxf(a[0], a[1]), fmaxf(a[2], a[3])));
        }
        mx = fmaxf(mx, __shfl_xor(mx, 16));
        mx = fmaxf(mx, __shfl_xor(mx, 32));
        if (q == 0) red[w * 256 + dt * 16 + dl] = mx;
    }
    __syncthreads();
    if (tid < 256) {
        float m0 = fmaxf(red[tid], red[256 + tid]);
        float m1 = fmaxf(red[512 + tid], red[768 + tid]);
        float m2 = fmaxf(red[1024 + tid], red[1280 + tid]);
        float m3 = fmaxf(red[1536 + tid], red[1792 + tid]);
        zv[tid] = fmaxf(fmaxf(m0, m1), fmaxf(m2, m3)) + b1[tid];
    }
    __syncthreads();

    // ---- GEMV: v[j] = sum_d zv[d] * w2zt[d][j], fp32, w2zt from L2 ----
    {
        const int jq = tid & 63;       // j quad (float4 column group)
        const int dpart = tid >> 6;    // d range [32*dpart, +32)
        const float4* wz4 = (const float4*)w2zt;
        float4 vacc = make_float4(0.f, 0.f, 0.f, 0.f);
#pragma unroll 4
        for (int d = 0; d < 32; ++d) {
            int dd = dpart * 32 + d;
            float s = zv[dd];
            float4 wv = wz4[dd * 64 + jq];
            vacc.x = fmaf(s, wv.x, vacc.x);
            vacc.y = fmaf(s, wv.y, vacc.y);
            vacc.z = fmaf(s, wv.z, vacc.z);
            vacc.w = fmaf(s, wv.w, vacc.w);
        }
        ((float4*)red)[dpart * 64 + jq] = vacc;
    }
    __syncthreads();
    if (tid < 256) {
        float s = red[tid] + red[256 + tid] + red[512 + tid] + red[768 + tid]
                + red[1024 + tid] + red[1280 + tid] + red[1536 + tid] + red[1792 + tid];
        vout[(size_t)bn * 256 + tid] = s;
    }
}

// ================= kernel B: out = x @ w2x^T + v (streaming GEMM) =================
// grid 4096 (2 blocks per bn, 128 rows each), 512 threads = 8 waves, 16 rows per wave.
// Weights staged in LDS once (k-padded hi/lo planes), one barrier, then a free-running
// dt loop: 4 ds_read_b128 -> 6 MFMA -> 4 stores. acc live = 4 VGPR; stores spread
// uniformly over the kernel. LDS 74.8 KB -> 2 blocks/CU = 16 waves/CU = 4 waves/SIMD.
__global__ __launch_bounds__(512, 4)
void pointnet_out(const float* __restrict__ x,
                  const short* __restrict__ w2xp,  // hi @0, lo @+16384 shorts
                  const float* __restrict__ vin,
                  float* __restrict__ out) {
    __shared__ short wlds[2 * PLANE];   // hi plane @0, lo plane @PLANE
    __shared__ float vsh[256];

    const int tid  = threadIdx.x;
    const int bn   = blockIdx.x >> 1;
    const int half = blockIdx.x & 1;
    const int l    = tid & 63;
    const int dl   = l & 15;
    const int q    = l >> 4;
    const int row0 = half * 128 + (tid >> 6) * 16;   // wave's 16-row strip

    // ---- stage w2x hi/lo planes into LDS (pad k 64->72) ----
    {
        const short8* src = (const short8*)w2xp;
#pragma unroll
        for (int it = 0; it < 8; ++it) {
            int i = tid + 512 * it;                 // i in [0,4096): 16B chunks
            int plane = i >> 11;                    // 2048 chunks per plane
            int c = i & 2047;
            int row = c >> 3, k = (c & 7) << 3;
            *(short8*)&wlds[plane * PLANE + row * KPAD + k] = src[i];
        }
    }
    if (tid < 256) vsh[tid] = vin[(size_t)bn * 256 + tid];

    // ---- A-frags: rows row0+dl, k = s*32+q*8 .. +7, split to bf16 hi/lo ----
    const float* __restrict__ xg = x + (size_t)bn * (256 * CIN);
    short8 ahi[2], alo[2];
#pragma unroll
    for (int s = 0; s < 2; ++s) {
        const float* p = xg + (row0 + dl) * CIN + s * 32 + q * 8;
        float4 x0 = *(const float4*)p;
        float4 x1 = *(const float4*)(p + 4);
        float e[8];
        e[0] = x0.x; e[1] = x0.y; e[2] = x0.z; e[3] = x0.w;
        e[4] = x1.x; e[5] = x1.y; e[6] = x1.z; e[7] = x1.w;
#pragma unroll
        for (int j = 0; j < 8; ++j) {
            short h = f2bf(e[j]);
            ahi[s][j] = h;
            alo[s][j] = f2bf(e[j] - bf2f(h));
        }
    }
    __syncthreads();

    float* __restrict__ og = out + (size_t)bn * 65536 + (size_t)row0 * 256;
#pragma unroll 2
    for (int dt = 0; dt < 16; ++dt) {
        const int off = (dt * 16 + dl) * KPAD + q * 8;
        short8 bh0 = *(const short8*)&wlds[off];
        short8 bh1 = *(const short8*)&wlds[off + 32];
        short8 bl0 = *(const short8*)&wlds[off + PLANE];
        short8 bl1 = *(const short8*)&wlds[off + PLANE + 32];
        float4v a = {0.f, 0.f, 0.f, 0.f};
        a = __builtin_amdgcn_mfma_f32_16x16x32_bf16(ahi[0], bh0, a, 0, 0, 0);
        a = __builtin_amdgcn_mfma_f32_16x16x32_bf16(ahi[0], bl0, a, 0, 0, 0);
        a = __builtin_amdgcn_mfma_f32_16x16x32_bf16(alo[0], bh0, a, 0, 0, 0);
        a = __builtin_amdgcn_mfma_f32_16x16x32_bf16(ahi[1], bh1, a, 0, 0, 0);
        a = __builtin_amdgcn_mfma_f32_16x16x32_bf16(ahi[1], bl1, a, 0, 0, 0);
        a = __builtin_amdgcn_mfma_f32_16x16x32_bf16(alo[1], bh1, a, 0, 0, 0);
        const float vd = vsh[dt * 16 + dl];
        const int cb = (q * 4) * 256 + dt * 16 + dl;   // C row = q*4+r, col = dt*16+dl
#pragma unroll
        for (int r = 0; r < 4; ++r)
            og[cb + r * 256] = a[r] + vd;
    }
}

extern "C" void kernel_launch(void* const* d_in, const int* in_sizes, int n_in,
                              void* d_out, int out_size, void* d_ws, size_t ws_size,
                              hipStream_t stream) {
    const float* x  = (const float*)d_in[0];
    const float* w1 = (const float*)d_in[1];
    const float* b1 = (const float*)d_in[2];
    const float* w2 = (const float*)d_in[3];
    short* wsS = (short*)d_ws;
    float* out = (float*)d_out;

    const float* w2zt = (const float*)(wsS + 65536);          // byte 128K
    float* vbuf = (float*)((char*)d_ws + 393216);             // byte 384K, 2 MB

    hipLaunchKernelGGL(prep_weights, dim3(384), dim3(256), 0, stream, w1, w2, wsS);
    hipLaunchKernelGGL(pointnet_v, dim3(2048), dim3(512), 0, stream,
                       x, b1, wsS, w2zt, vbuf);
    hipLaunchKernelGGL(pointnet_out, dim3(4096), dim3(512), 0, stream,
                       x, wsS + 32768, vbuf, out);
}